// Round 2
// baseline (315.949 us; speedup 1.0000x reference)
//
#include <hip/hip_runtime.h>
#include <stdint.h>

#define HW   4096
#define CIN  512

typedef __attribute__((ext_vector_type(8))) short short8;
typedef __attribute__((ext_vector_type(4))) float f32x4;
typedef unsigned short u16;

__device__ __forceinline__ u16 f2bf(float f) {
  union { float f; uint32_t u; } c; c.f = f;
  uint32_t r = (c.u + 0x7FFFu + ((c.u >> 16) & 1u)) >> 16;
  return (u16)r;
}
__device__ __forceinline__ float bf2f(u16 h) {
  union { uint32_t u; float f; } c; c.u = ((uint32_t)h) << 16;
  return c.f;
}

// ---------------------------------------------------------------------------
// x (B,C,HW) fp32  ->  xbT (B*HW, C) bf16   (64x64 tile transpose via LDS)
// grid (HW/64, C/64, B), 256 threads
// ---------------------------------------------------------------------------
__global__ __launch_bounds__(256) void cast_xT(const float* __restrict__ x,
                                               u16* __restrict__ xbT) {
  __shared__ u16 t[64 * 72];
  int p0 = blockIdx.x * 64, c0 = blockIdx.y * 64, b = blockIdx.z;
  int tid = threadIdx.x, r = tid >> 2, ch = tid & 3;
  const float* xp = x + ((size_t)b * CIN + c0 + r) * HW + p0 + ch * 16;
  float4 f0 = *(const float4*)(xp + 0);
  float4 f1 = *(const float4*)(xp + 4);
  float4 f2 = *(const float4*)(xp + 8);
  float4 f3 = *(const float4*)(xp + 12);
  u16* tr = &t[r * 72 + ch * 16];
  tr[0] = f2bf(f0.x); tr[1] = f2bf(f0.y); tr[2] = f2bf(f0.z); tr[3] = f2bf(f0.w);
  tr[4] = f2bf(f1.x); tr[5] = f2bf(f1.y); tr[6] = f2bf(f1.z); tr[7] = f2bf(f1.w);
  tr[8] = f2bf(f2.x); tr[9] = f2bf(f2.y); tr[10] = f2bf(f2.z); tr[11] = f2bf(f2.w);
  tr[12] = f2bf(f3.x); tr[13] = f2bf(f3.y); tr[14] = f2bf(f3.z); tr[15] = f2bf(f3.w);
  __syncthreads();
  u16 o[16];
#pragma unroll
  for (int j = 0; j < 16; j++) o[j] = t[(ch * 16 + j) * 72 + r];
  u16* op = xbT + ((size_t)b * HW + p0 + r) * CIN + c0 + ch * 16;
  *(short8*)(op) = *(short8*)&o[0];
  *(short8*)(op + 8) = *(short8*)&o[8];
}

// ---------------------------------------------------------------------------
// weights -> bf16; wqk = [Wq;Wk] (128,512); bqk = [bq;bk]
// ---------------------------------------------------------------------------
__global__ void cast_w(const float* __restrict__ Wq, const float* __restrict__ Wk,
                       const float* __restrict__ Wv, const float* __restrict__ Wd,
                       const float* __restrict__ bq, const float* __restrict__ bk,
                       u16* __restrict__ wqk, u16* __restrict__ wv,
                       u16* __restrict__ wd, float* __restrict__ bqk) {
  int i = blockIdx.x * 256 + threadIdx.x;
  if (i < 65536) wqk[i] = f2bf(i < 32768 ? Wq[i] : Wk[i - 32768]);
  if (i < 262144) { wv[i] = f2bf(Wv[i]); wd[i] = f2bf(Wd[i]); }
  if (i < 128) bqk[i] = (i < 64) ? bq[i] : bk[i - 64];
}

// ---------------------------------------------------------------------------
// Generic GEMM: C(M,N) = A(M,K) * BT(N,K)^T  (both bf16, K-contiguous rows)
// 128x128 tile, BK=32, 256 thr / 4 waves, each wave 64x64 (4x4 mfma tiles).
// Staging: each thread loads rows srow and srow+64 (8 bf16 each) per matrix.
// mode 0: out row-major (M,N) bf16, bias[col]
// mode 1: out (B, M, HW) bf16, col=b*HW+p, bias[row]
// mode 2: out (B, M, HW) fp32, bias[row]
// ---------------------------------------------------------------------------
__global__ __launch_bounds__(256) void gemm_bf16(
    const u16* __restrict__ A, const u16* __restrict__ BT,
    const float* __restrict__ bias, void* __restrict__ out,
    int M, int N, int K, int mode) {
  __shared__ u16 lds_a[128 * 40];
  __shared__ u16 lds_b[128 * 40];
  int tid = threadIdx.x;
  int w = tid >> 6, lane = tid & 63, m = lane & 15, g = lane >> 4;
  int wm = w >> 1, wn = w & 1;
  int m0 = blockIdx.y * 128, n0 = blockIdx.x * 128;
  int srow = tid >> 2, sch = tid & 3;
  const u16* pa = A + (size_t)(m0 + srow) * K + sch * 8;
  const u16* pb = BT + (size_t)(n0 + srow) * K + sch * 8;
  size_t rstep = (size_t)64 * K;

  f32x4 acc[4][4];
  f32x4 zero = {0.f, 0.f, 0.f, 0.f};
#pragma unroll
  for (int i = 0; i < 4; i++)
#pragma unroll
    for (int j = 0; j < 4; j++) acc[i][j] = zero;

  for (int k0 = 0; k0 < K; k0 += 32) {
    short8 av0 = *(const short8*)(pa + k0);
    short8 av1 = *(const short8*)(pa + rstep + k0);
    short8 bv0 = *(const short8*)(pb + k0);
    short8 bv1 = *(const short8*)(pb + rstep + k0);
    __syncthreads();
    *(short8*)&lds_a[srow * 40 + sch * 8] = av0;
    *(short8*)&lds_a[(srow + 64) * 40 + sch * 8] = av1;
    *(short8*)&lds_b[srow * 40 + sch * 8] = bv0;
    *(short8*)&lds_b[(srow + 64) * 40 + sch * 8] = bv1;
    __syncthreads();
    short8 af[4], bf[4];
#pragma unroll
    for (int i = 0; i < 4; i++)
      af[i] = *(const short8*)&lds_a[(wm * 64 + i * 16 + m) * 40 + g * 8];
#pragma unroll
    for (int j = 0; j < 4; j++)
      bf[j] = *(const short8*)&lds_b[(wn * 64 + j * 16 + m) * 40 + g * 8];
#pragma unroll
    for (int i = 0; i < 4; i++)
#pragma unroll
      for (int j = 0; j < 4; j++)
        acc[i][j] = __builtin_amdgcn_mfma_f32_16x16x32_bf16(af[i], bf[j], acc[i][j], 0, 0, 0);
  }

#pragma unroll
  for (int i = 0; i < 4; i++) {
#pragma unroll
    for (int j = 0; j < 4; j++) {
      int row_l = m0 + wm * 64 + i * 16 + g * 4;
      int col = n0 + wn * 64 + j * 16 + m;
#pragma unroll
      for (int r = 0; r < 4; r++) {
        int row = row_l + r;
        float v = acc[i][j][r];
        if (mode == 0) {
          v += bias[col];
          ((u16*)out)[(size_t)row * N + col] = f2bf(v);
        } else {
          v += bias[row];
          size_t addr = ((size_t)(col >> 12) * M + row) * HW + (col & (HW - 1));
          if (mode == 1) ((u16*)out)[addr] = f2bf(v);
          else           ((float*)out)[addr] = v;
        }
      }
    }
  }
}

// ---------------------------------------------------------------------------
// Fused attention + residual: per block (b, 64-row i-tile):
//   S = Q K^T (64x4096), softmax over j (two-pass), O = P V', then
//   uT[p][c] = gamma*O + x  (bf16)
// qkT: (B*HW, 128)  cols 0..63 = q, 64..127 = k
// V:   (B, 512, HW) bf16;  xbT/uT: (B*HW, 512) bf16
// 512 threads (8 waves). S-phase: wave w -> i-subtile (w>>1), j-half (w&1).
// PV-phase: wave w -> channels [w*64, w*64+64).
// ---------------------------------------------------------------------------
__global__ __launch_bounds__(512) void attn_fused(
    const u16* __restrict__ qkT, const u16* __restrict__ V,
    const u16* __restrict__ xbT, const float* __restrict__ gamma,
    u16* __restrict__ uT) {
  __shared__ u16 v_lds[512 * 72];
  __shared__ u16 p_lds[64 * 72];
  __shared__ float2 part[2][64];
  __shared__ float sm_m[64];
  __shared__ float sm_li[64];

  int tid = threadIdx.x;
  int w = tid >> 6, lane = tid & 63, m = lane & 15, g = lane >> 4;
  int b = blockIdx.x >> 6;
  int i0 = (blockIdx.x & 63) << 6;
  int it = w >> 1, jh = w & 1;
  size_t qbase = (size_t)b * HW + i0;

  short8 aq[2];
#pragma unroll
  for (int ks = 0; ks < 2; ks++)
    aq[ks] = *(const short8*)(qkT + (qbase + it * 16 + m) * 128 + ks * 32 + g * 8);

  // ---- pass A: row max / sumexp (online, scalars only) ----
  float mr[4], lr[4];
#pragma unroll
  for (int r = 0; r < 4; r++) { mr[r] = -1e30f; lr[r] = 0.f; }

  for (int j0 = 0; j0 < HW; j0 += 64) {
    size_t kbase = (size_t)b * HW + j0;
    f32x4 sv[2];
#pragma unroll
    for (int jj = 0; jj < 2; jj++) {
      int jt = jh * 2 + jj;
      f32x4 s = {0.f, 0.f, 0.f, 0.f};
#pragma unroll
      for (int ks = 0; ks < 2; ks++) {
        short8 bk = *(const short8*)(qkT + (kbase + jt * 16 + m) * 128 + 64 + ks * 32 + g * 8);
        s = __builtin_amdgcn_mfma_f32_16x16x32_bf16(aq[ks], bk, s, 0, 0, 0);
      }
      sv[jj] = s;
    }
#pragma unroll
    for (int r = 0; r < 4; r++) {
      float v0 = sv[0][r], v1 = sv[1][r];
      float nm = fmaxf(mr[r], fmaxf(v0, v1));
      lr[r] = lr[r] * __expf(mr[r] - nm) + __expf(v0 - nm) + __expf(v1 - nm);
      mr[r] = nm;
    }
  }
  // reduce across the 16 column-lanes
#pragma unroll
  for (int r = 0; r < 4; r++) {
#pragma unroll
    for (int off = 1; off < 16; off <<= 1) {
      float om = __shfl_xor(mr[r], off);
      float ol = __shfl_xor(lr[r], off);
      float nm = fmaxf(mr[r], om);
      lr[r] = lr[r] * __expf(mr[r] - nm) + ol * __expf(om - nm);
      mr[r] = nm;
    }
  }
  if (m == 0) {
#pragma unroll
    for (int r = 0; r < 4; r++)
      part[jh][it * 16 + g * 4 + r] = make_float2(mr[r], lr[r]);
  }
  __syncthreads();
  if (tid < 64) {
    float2 a = part[0][tid], c = part[1][tid];
    float mm = fmaxf(a.x, c.x);
    float ll = a.y * __expf(a.x - mm) + c.y * __expf(c.x - mm);
    sm_m[tid] = mm;
    sm_li[tid] = 1.0f / ll;
  }
  __syncthreads();

  // ---- pass B: P = exp(S - m), O += P*V ----
  f32x4 acc[4][4];
  f32x4 zero = {0.f, 0.f, 0.f, 0.f};
#pragma unroll
  for (int i = 0; i < 4; i++)
#pragma unroll
    for (int j = 0; j < 4; j++) acc[i][j] = zero;

  const u16* vbase = V + (size_t)b * CIN * HW;
  for (int j0 = 0; j0 < HW; j0 += 64) {
    // stage V tile (issue loads early; write to LDS after S compute)
    short8 vst[8];
#pragma unroll
    for (int l = 0; l < 8; l++)
      vst[l] = *(const short8*)(vbase + (size_t)(l * 64 + (tid >> 3)) * HW + j0 + (tid & 7) * 8);

    size_t kbase = (size_t)b * HW + j0;
#pragma unroll
    for (int jj = 0; jj < 2; jj++) {
      int jt = jh * 2 + jj;
      f32x4 s = {0.f, 0.f, 0.f, 0.f};
#pragma unroll
      for (int ks = 0; ks < 2; ks++) {
        short8 bk = *(const short8*)(qkT + (kbase + jt * 16 + m) * 128 + 64 + ks * 32 + g * 8);
        s = __builtin_amdgcn_mfma_f32_16x16x32_bf16(aq[ks], bk, s, 0, 0, 0);
      }
#pragma unroll
      for (int r = 0; r < 4; r++) {
        int il = it * 16 + g * 4 + r;
        float p = __expf(s[r] - sm_m[il]);
        p_lds[il * 72 + jt * 16 + m] = f2bf(p);
      }
    }
#pragma unroll
    for (int l = 0; l < 8; l++)
      *(short8*)&v_lds[(l * 64 + (tid >> 3)) * 72 + (tid & 7) * 8] = vst[l];
    __syncthreads();

#pragma unroll
    for (int ks = 0; ks < 2; ks++) {
      short8 pa[4], vb[4];
#pragma unroll
      for (int i2 = 0; i2 < 4; i2++)
        pa[i2] = *(const short8*)&p_lds[(i2 * 16 + m) * 72 + ks * 32 + g * 8];
#pragma unroll
      for (int ct = 0; ct < 4; ct++)
        vb[ct] = *(const short8*)&v_lds[(w * 64 + ct * 16 + m) * 72 + ks * 32 + g * 8];
#pragma unroll
      for (int i2 = 0; i2 < 4; i2++)
#pragma unroll
        for (int ct = 0; ct < 4; ct++)
          acc[i2][ct] = __builtin_amdgcn_mfma_f32_16x16x32_bf16(pa[i2], vb[ct], acc[i2][ct], 0, 0, 0);
    }
    __syncthreads();
  }

  // ---- epilogue: uT = gamma * (acc / l) + x ----
  float gm = gamma[0];
#pragma unroll
  for (int i2 = 0; i2 < 4; i2++) {
#pragma unroll
    for (int ct = 0; ct < 4; ct++) {
#pragma unroll
      for (int r = 0; r < 4; r++) {
        int il = i2 * 16 + g * 4 + r;
        float o = acc[i2][ct][r] * sm_li[il];
        size_t row = qbase + il;
        int c = w * 64 + ct * 16 + m;
        float xv = bf2f(xbT[row * CIN + c]);
        uT[row * CIN + c] = f2bf(gm * o + xv);
      }
    }
  }
}

// ---------------------------------------------------------------------------
extern "C" void kernel_launch(void* const* d_in, const int* in_sizes, int n_in,
                              void* d_out, int out_size, void* d_ws, size_t ws_size,
                              hipStream_t stream) {
  const float* x     = (const float*)d_in[0];
  const float* Wq    = (const float*)d_in[1];
  const float* bq    = (const float*)d_in[2];
  const float* Wk    = (const float*)d_in[3];
  const float* bk    = (const float*)d_in[4];
  const float* Wv    = (const float*)d_in[5];
  const float* bv    = (const float*)d_in[6];
  const float* gamma = (const float*)d_in[7];
  const float* Wd    = (const float*)d_in[8];
  const float* bd    = (const float*)d_in[9];

  char* ws = (char*)d_ws;
  size_t off = 0;
  auto alloc = [&](size_t bytes) {
    void* p = ws + off;
    off += (bytes + 255) & ~(size_t)255;
    return p;
  };
  u16*   xbT = (u16*)alloc((size_t)16384 * 512 * 2);
  u16*   qkT = (u16*)alloc((size_t)16384 * 128 * 2);
  u16*   vb  = (u16*)alloc((size_t)16384 * 512 * 2);
  u16*   uT  = (u16*)alloc((size_t)16384 * 512 * 2);
  u16*   wqk = (u16*)alloc((size_t)65536 * 2);
  u16*   wvb = (u16*)alloc((size_t)262144 * 2);
  u16*   wdb = (u16*)alloc((size_t)262144 * 2);
  float* bqk = (float*)alloc(128 * 4);
  if (off > ws_size) return;  // workspace too small -> fail loudly (poison stays)

  cast_xT<<<dim3(64, 8, 4), 256, 0, stream>>>(x, xbT);
  cast_w<<<1024, 256, 0, stream>>>(Wq, Wk, Wv, Wd, bq, bk, wqk, wvb, wdb, bqk);
  // qkT (16384,128) = xbT (16384,512) * wqk^T
  gemm_bf16<<<dim3(1, 128), 256, 0, stream>>>(xbT, wqk, bqk, qkT, 16384, 128, 512, 0);
  // v (B,512,HW) = Wv * x
  gemm_bf16<<<dim3(128, 4), 256, 0, stream>>>(wvb, xbT, bv, vb, 512, 16384, 512, 1);
  // attention + residual -> uT (16384,512)
  attn_fused<<<dim3(256), 512, 0, stream>>>(qkT, vb, xbT, gamma, uT);
  // pam_out (B,512,HW) fp32 = Wd * u
  gemm_bf16<<<dim3(128, 4), 256, 0, stream>>>(wdb, uT, bd, d_out, 512, 16384, 512, 2);
}